// Round 9
// baseline (189.790 us; speedup 1.0000x reference)
//
#include <hip/hip_runtime.h>

#define NN 50000
#define NE 100000
#define IN_F 63
#define HID 64
#define NREL 8
#define NK (NREL * NN)                       // 400000 sort buckets (t*NN + r)
#define SCAN_BLKS ((NK + 255) / 256)         // 1563
#define W 32                                 // edges per wave in edge kernel
#define NWAVES ((NE + W - 1) / W)            // 3125
#define R1_BLOCKS 2048

// ---- stage 1: bucket counts cnt[t*NN+r] + sender degree -------------------
__global__ __launch_bounds__(256) void count_kernel(const int* __restrict__ senders,
                                                    const int* __restrict__ receivers,
                                                    const int* __restrict__ etypes,
                                                    int* __restrict__ cnt,
                                                    int* __restrict__ scnt) {
    int e = blockIdx.x * 256 + threadIdx.x;
    if (e < NE) {
        atomicAdd(&cnt[etypes[e] * NN + receivers[e]], 1);
        atomicAdd(&scnt[senders[e]], 1);
    }
}

// ---- scan L1: per-256-block exclusive scan of cnt -> offs, totals -> bsum -
__global__ __launch_bounds__(256) void scan1_kernel(const int* __restrict__ cnt,
                                                    int* __restrict__ offs,
                                                    int* __restrict__ bsum) {
    int i = blockIdx.x * 256 + threadIdx.x;
    int c = (i < NK) ? cnt[i] : 0;
    int lane = threadIdx.x & 63, wv = threadIdx.x >> 6;
    int x = c;
#pragma unroll
    for (int o = 1; o < 64; o <<= 1) {
        int y = __shfl_up(x, o, 64);
        if (lane >= o) x += y;
    }
    __shared__ int wtot[4];
    if (lane == 63) wtot[wv] = x;
    __syncthreads();
    int base = 0;
#pragma unroll
    for (int k = 0; k < 4; ++k) if (k < wv) base += wtot[k];
    if (i < NK) offs[i] = base + x - c;
    if (threadIdx.x == 255) bsum[blockIdx.x] = base + x;
}

// ---- scan L2: one block scans the 1563 block sums (serial 256-chunks) -----
__global__ __launch_bounds__(256) void scan2_kernel(const int* __restrict__ bsum,
                                                    int* __restrict__ bbase) {
    __shared__ int wtot[4];
    __shared__ int carry;
    if (threadIdx.x == 0) carry = 0;
    __syncthreads();
    const int lane = threadIdx.x & 63, wv = threadIdx.x >> 6;
    for (int b = 0; b < SCAN_BLKS; b += 256) {
        const int i = b + threadIdx.x;
        const int c = (i < SCAN_BLKS) ? bsum[i] : 0;
        int x = c;
#pragma unroll
        for (int o = 1; o < 64; o <<= 1) {
            int y = __shfl_up(x, o, 64);
            if (lane >= o) x += y;
        }
        if (lane == 63) wtot[wv] = x;
        __syncthreads();
        int base = 0;
#pragma unroll
        for (int k = 0; k < 4; ++k) if (k < wv) base += wtot[k];
        if (i < SCAN_BLKS) bbase[i] = carry + base + x - c;
        const int btot = wtot[0] + wtot[1] + wtot[2] + wtot[3];
        __syncthreads();
        if (threadIdx.x == 0) carry += btot;
        __syncthreads();
    }
}

// ---- scan L3: globalize offs, init cursor, offs[NK]=NE, build rdeg --------
__global__ __launch_bounds__(256) void scan3_kernel(int* __restrict__ offs,
                                                    const int* __restrict__ bbase,
                                                    int* __restrict__ cursor,
                                                    const int* __restrict__ cnt,
                                                    float* __restrict__ rdeg) {
    int i = blockIdx.x * 256 + threadIdx.x;
    if (i < NK) {
        int v = offs[i] + bbase[i >> 8];
        offs[i] = v;
        cursor[i] = v;
    }
    if (i == 0) offs[NK] = NE;
    if (i < NN) {
        int d = 0;
#pragma unroll
        for (int t = 0; t < NREL; ++t) d += cnt[t * NN + i];
        rdeg[i] = (float)d;
    }
}

// ---- stage 3: scatter edges into (relation, receiver)-sorted order --------
__global__ __launch_bounds__(256) void scatter_kernel(const int* __restrict__ senders,
                                                      const int* __restrict__ receivers,
                                                      const int* __restrict__ etypes,
                                                      const int* __restrict__ scnt,
                                                      int* __restrict__ cursor,
                                                      int* __restrict__ m32,
                                                      unsigned short* __restrict__ r16,
                                                      float* __restrict__ ns_srt) {
    int e = blockIdx.x * 256 + threadIdx.x;
    if (e < NE) {
        const int r = receivers[e], s = senders[e], t = etypes[e];
        const int pos = atomicAdd(&cursor[t * NN + r], 1);
        m32[pos] = s | (t << 16);                 // s<2^16, t in bits 16..18
        r16[pos] = (unsigned short)r;
        ns_srt[pos] = rsqrtf(fmaxf((float)scnt[s], 1.0f));
    }
}

// ---- edge kernel: sorted stream, kcol-in-VGPR, run-aggregated atomics -----
// Wave = 32 consecutive sorted edges (single relation except <=7 boundary
// waves -> uniform kcol reload). Same-receiver runs accumulate in registers
// and emit ONE 256B atomicAdd per run: atomic lane-ops 6.4M -> ~2.9M
// (r4/r6 evidence: plain-f32 scatter atomics were the ~43us floor; packed
// f32 atomics don't exist on gfx950; r8: per-edge relation scan is latency
// death — the sort removes both).
__global__ __launch_bounds__(256) void edge_kernel(const float* __restrict__ nodes,
                                                   const float* __restrict__ kernels,
                                                   const int* __restrict__ m32,
                                                   const unsigned short* __restrict__ r16,
                                                   const float* __restrict__ ns_srt,
                                                   float* __restrict__ agg) {
    const int lane = threadIdx.x & 63;
    const int wid = blockIdx.x * 4 + (threadIdx.x >> 6);
    const int base = wid * W;
    if (base >= NE) return;
    const int lim = min(base + W, NE);

    // lanes preload the window's metadata (halves mirror via lane&31)
    const int el = base + (lane & 31);
    int m_l = 0, r_l = 0;
    float ns_l = 0.f;
    if (el < lim) {
        m_l  = m32[el];
        r_l  = (int)r16[el];
        ns_l = ns_srt[el];
    }

    float kcol[IN_F];
    int cur_t = -1;
    int cur_r = -1;
    float racc = 0.f;

    for (int j = base; j < lim; ++j) {
        const int idx = j - base;
        const int   mv = __shfl(m_l, idx);
        const int   r  = __shfl(r_l, idx);
        const float ns = __shfl(ns_l, idx);
        const int   t  = (mv >> 16) & 7;
        const int   s  = mv & 0xFFFF;

        if (t != cur_t) {                         // uniform; ~once per wave
            const float* Kt = kernels + (size_t)t * IN_F * HID;
#pragma unroll
            for (int i = 0; i < IN_F; ++i) kcol[i] = Kt[i * HID + lane];
            cur_t = t;
        }
        if (r != cur_r) {                         // run boundary: emit
            if (cur_r >= 0)
                atomicAdd(&agg[(size_t)cur_r * HID + lane], racc);
            racc = 0.f;
            cur_r = r;
        }
        const float4* x4 = (const float4*)(nodes + (size_t)s * (IN_F + 1));
        float a0 = 0.f, a1 = 0.f, a2 = 0.f, a3 = 0.f;
#pragma unroll
        for (int jj = 0; jj < 16; ++jj) {
            const float4 v = x4[jj];
            a0 = fmaf(kcol[4 * jj + 0], v.x, a0);
            a1 = fmaf(kcol[4 * jj + 1], v.y, a1);
            a2 = fmaf(kcol[4 * jj + 2], v.z, a2);
            if (4 * jj + 3 < IN_F) a3 = fmaf(kcol[4 * jj + 3], v.w, a3);
        }
        racc = fmaf((a0 + a1) + (a2 + a3), ns, racc);
    }
    if (cur_r >= 0)
        atomicAdd(&agg[(size_t)cur_r * HID + lane], racc);
}

// ---- readout stage 1: per-block partial, plain store (r7 proven) ----------
__global__ __launch_bounds__(256) void readout1_kernel(const float* __restrict__ nodes,
                                                       const float* __restrict__ agg,
                                                       const float* __restrict__ rdeg,
                                                       const float* __restrict__ w,
                                                       float* __restrict__ partial) {
    __shared__ float wsum[4];
    const int lane = threadIdx.x & 63;
    const int wid  = threadIdx.x >> 6;
    const int gw = blockIdx.x * 4 + wid;
    const int nw = R1_BLOCKS * 4;
    const float wf = w[lane];

    float local = 0.f;
    for (int n = gw; n < NN; n += nw) {
        float a = agg[(size_t)n * HID + lane];
        float nr = rsqrtf(fmaxf(rdeg[n], 1.0f));
        float root = nodes[(size_t)n * (IN_F + 1) + IN_F];  // wave-uniform
        local += fmaxf(a * nr, 0.f) * root;
    }
    float v = local * wf;
#pragma unroll
    for (int o = 32; o > 0; o >>= 1) v += __shfl_xor(v, o, 64);
    if (lane == 0) wsum[wid] = v;
    __syncthreads();
    if (threadIdx.x == 0)
        partial[blockIdx.x] = (wsum[0] + wsum[1]) + (wsum[2] + wsum[3]);
}

// ---- readout stage 2: one block sums partials + bias ----------------------
__global__ __launch_bounds__(256) void readout2_kernel(const float* __restrict__ partial,
                                                       const float* __restrict__ b,
                                                       float* __restrict__ out) {
    __shared__ float wsum[4];
    const int lane = threadIdx.x & 63;
    const int wid  = threadIdx.x >> 6;
    float v = 0.f;
    for (int i = threadIdx.x; i < R1_BLOCKS; i += 256) v += partial[i];
#pragma unroll
    for (int o = 32; o > 0; o >>= 1) v += __shfl_xor(v, o, 64);
    if (lane == 0) wsum[wid] = v;
    __syncthreads();
    if (threadIdx.x == 0)
        out[0] = (wsum[0] + wsum[1]) + (wsum[2] + wsum[3]) + b[0];
}

extern "C" void kernel_launch(void* const* d_in, const int* in_sizes, int n_in,
                              void* d_out, int out_size, void* d_ws, size_t ws_size,
                              hipStream_t stream) {
    const float* nodes     = (const float*)d_in[0];
    const int*   senders   = (const int*)d_in[1];
    const int*   receivers = (const int*)d_in[2];
    const int*   etypes    = (const int*)d_in[3];
    // d_in[4] = n_node (single graph; unused)
    const float* kernels   = (const float*)d_in[5];
    const float* dense_w   = (const float*)d_in[6];
    const float* dense_b   = (const float*)d_in[7];
    float* out = (float*)d_out;

    // workspace layout
    int*   cnt     = (int*)d_ws;                       // NK
    int*   scnt    = cnt + NK;                         // NN   (adjacent: one memset)
    int*   offs    = scnt + NN;                        // NK+1
    int*   cursor  = offs + NK + 1;                    // NK
    int*   bsum    = cursor + NK;                      // SCAN_BLKS
    int*   bbase   = bsum + SCAN_BLKS;                 // SCAN_BLKS
    int*   m32     = bbase + SCAN_BLKS;                // NE
    unsigned short* r16 = (unsigned short*)(m32 + NE); // NE (u16)
    float* ns_srt  = (float*)(r16 + NE + (NE & 1));    // NE
    float* rdeg    = ns_srt + NE;                      // NN
    float* partial = rdeg + NN;                        // R1_BLOCKS
    float* agg     = partial + R1_BLOCKS;              // NN x HID

    (void)hipMemsetAsync(cnt, 0, (NK + NN) * sizeof(int), stream);
    (void)hipMemsetAsync(agg, 0, (size_t)NN * HID * sizeof(float), stream);

    count_kernel<<<(NE + 255) / 256, 256, 0, stream>>>(senders, receivers, etypes,
                                                       cnt, scnt);
    scan1_kernel<<<SCAN_BLKS, 256, 0, stream>>>(cnt, offs, bsum);
    scan2_kernel<<<1, 256, 0, stream>>>(bsum, bbase);
    scan3_kernel<<<SCAN_BLKS, 256, 0, stream>>>(offs, bbase, cursor, cnt, rdeg);
    scatter_kernel<<<(NE + 255) / 256, 256, 0, stream>>>(senders, receivers, etypes,
                                                         scnt, cursor, m32, r16, ns_srt);

    const int eblocks = (NWAVES + 3) / 4;              // 782
    edge_kernel<<<eblocks, 256, 0, stream>>>(nodes, kernels, m32, r16, ns_srt, agg);

    readout1_kernel<<<R1_BLOCKS, 256, 0, stream>>>(nodes, agg, rdeg, dense_w, partial);
    readout2_kernel<<<1, 256, 0, stream>>>(partial, dense_b, out);
}

// Round 10
// 138.618 us; speedup vs baseline: 1.3692x; 1.3692x over previous
//
#include <hip/hip_runtime.h>

#define NN 50000
#define NE 100000
#define IN_F 63
#define HID 64
#define NREL 8
#define CHUNK 64
#define R1_BLOCKS 2048

// ---------------- degree kernel: float histograms of senders/receivers ----
__global__ __launch_bounds__(256) void deg_kernel(const int* __restrict__ senders,
                                                  const int* __restrict__ receivers,
                                                  float* __restrict__ sdeg,
                                                  float* __restrict__ rdeg) {
    int e = blockIdx.x * 256 + threadIdx.x;
    if (e < NE) {
        atomicAdd(&sdeg[senders[e]], 1.0f);
        atomicAdd(&rdeg[receivers[e]], 1.0f);
    }
}

// ---------------- edge kernel: 4 edges per iteration -----------------------
// r9 falsified the atomic-count theory (fewer atomics, slower): the binding
// constraint is memory LATENCY on random sender-row gathers. Fix: maximize
// per-wave MLP — 4 independent edges per iteration (64 float4 loads in
// flight, 8 indep FMA chains), metadata shuffles amortized.
__global__ __launch_bounds__(256) void edge_kernel(const float* __restrict__ nodes,
                                                   const int* __restrict__ senders,
                                                   const int* __restrict__ receivers,
                                                   const int* __restrict__ etypes,
                                                   const float* __restrict__ kernels,
                                                   const float* __restrict__ sdeg,
                                                   float* __restrict__ agg) {
    const int lane = threadIdx.x & 63;
    const int t = blockIdx.x & (NREL - 1);
    const int chunk = (blockIdx.x >> 3) * 4 + (threadIdx.x >> 6);
    const int base = chunk * CHUNK;
    if (base >= NE) return;
    const int lim = min(base + CHUNK, NE);

    float kcol[IN_F];
    const float* Kt = kernels + (size_t)t * IN_F * HID;
#pragma unroll
    for (int i = 0; i < IN_F; ++i) kcol[i] = Kt[i * HID + lane];

    const int e = base + lane;
    int pack_l = 0, ty = -1, s_tmp = 0;
    if (e < lim) {
        ty     = etypes[e];
        s_tmp  = senders[e];
        pack_l = s_tmp | (receivers[e] << 16);
    }
    float ns_l = 1.0f;
    if (ty == t) ns_l = rsqrtf(fmaxf(sdeg[s_tmp], 1.0f));

    unsigned long long m = __ballot(ty == t);
    while (m) {
        const int i0 = __builtin_ctzll(m); m &= m - 1;
        const bool h1 = (m != 0);
        const int i1 = h1 ? __builtin_ctzll(m) : i0;
        if (h1) m &= m - 1;
        const bool h2 = (m != 0);
        const int i2 = h2 ? __builtin_ctzll(m) : i0;
        if (h2) m &= m - 1;
        const bool h3 = (m != 0);
        const int i3 = h3 ? __builtin_ctzll(m) : i0;
        if (h3) m &= m - 1;

        const int   p0  = __builtin_amdgcn_readfirstlane(__shfl(pack_l, i0));
        const float ns0 = __shfl(ns_l, i0);
        const int   p1  = __builtin_amdgcn_readfirstlane(__shfl(pack_l, i1));
        const float ns1 = __shfl(ns_l, i1);
        const int   p2  = __builtin_amdgcn_readfirstlane(__shfl(pack_l, i2));
        const float ns2 = __shfl(ns_l, i2);
        const int   p3  = __builtin_amdgcn_readfirstlane(__shfl(pack_l, i3));
        const float ns3 = __shfl(ns_l, i3);

        const float4* xa = (const float4*)(nodes + (size_t)(p0 & 0xFFFF) * (IN_F + 1));
        const float4* xb = (const float4*)(nodes + (size_t)(p1 & 0xFFFF) * (IN_F + 1));
        const float4* xc = (const float4*)(nodes + (size_t)(p2 & 0xFFFF) * (IN_F + 1));
        const float4* xd = (const float4*)(nodes + (size_t)(p3 & 0xFFFF) * (IN_F + 1));

        float a0 = 0.f, a1 = 0.f, b0 = 0.f, b1 = 0.f;
        float c0 = 0.f, c1 = 0.f, d0 = 0.f, d1 = 0.f;
#pragma unroll
        for (int j = 0; j < 16; ++j) {
            const float4 va = xa[j];
            const float4 vb = xb[j];
            const float4 vc = xc[j];
            const float4 vd = xd[j];
            const float k0 = kcol[4 * j + 0], k1 = kcol[4 * j + 1];
            const float k2 = kcol[4 * j + 2];
            const float k3 = (4 * j + 3 < IN_F) ? kcol[4 * j + 3] : 0.f;
            a0 = fmaf(k0, va.x, a0); a1 = fmaf(k1, va.y, a1);
            a0 = fmaf(k2, va.z, a0); a1 = fmaf(k3, va.w, a1);
            b0 = fmaf(k0, vb.x, b0); b1 = fmaf(k1, vb.y, b1);
            b0 = fmaf(k2, vb.z, b0); b1 = fmaf(k3, vb.w, b1);
            c0 = fmaf(k0, vc.x, c0); c1 = fmaf(k1, vc.y, c1);
            c0 = fmaf(k2, vc.z, c0); c1 = fmaf(k3, vc.w, c1);
            d0 = fmaf(k0, vd.x, d0); d1 = fmaf(k1, vd.y, d1);
            d0 = fmaf(k2, vd.z, d0); d1 = fmaf(k3, vd.w, d1);
        }
        atomicAdd(&agg[(size_t)(((unsigned)p0) >> 16) * HID + lane], (a0 + a1) * ns0);
        if (h1) atomicAdd(&agg[(size_t)(((unsigned)p1) >> 16) * HID + lane], (b0 + b1) * ns1);
        if (h2) atomicAdd(&agg[(size_t)(((unsigned)p2) >> 16) * HID + lane], (c0 + c1) * ns2);
        if (h3) atomicAdd(&agg[(size_t)(((unsigned)p3) >> 16) * HID + lane], (d0 + d1) * ns3);
    }
}

// ---- readout stage 1: per-block partial, plain store (r7 proven) ----------
__global__ __launch_bounds__(256) void readout1_kernel(const float* __restrict__ nodes,
                                                       const float* __restrict__ agg,
                                                       const float* __restrict__ rdeg,
                                                       const float* __restrict__ w,
                                                       float* __restrict__ partial) {
    __shared__ float wsum[4];
    const int lane = threadIdx.x & 63;
    const int wid  = threadIdx.x >> 6;
    const int gw = blockIdx.x * 4 + wid;
    const int nw = R1_BLOCKS * 4;
    const float wf = w[lane];

    float local = 0.f;
    for (int n = gw; n < NN; n += nw) {
        float a = agg[(size_t)n * HID + lane];
        float nr = rsqrtf(fmaxf(rdeg[n], 1.0f));
        float root = nodes[(size_t)n * (IN_F + 1) + IN_F];  // wave-uniform
        local += fmaxf(a * nr, 0.f) * root;
    }
    float v = local * wf;
#pragma unroll
    for (int o = 32; o > 0; o >>= 1) v += __shfl_xor(v, o, 64);
    if (lane == 0) wsum[wid] = v;
    __syncthreads();
    if (threadIdx.x == 0)
        partial[blockIdx.x] = (wsum[0] + wsum[1]) + (wsum[2] + wsum[3]);
}

// ---- readout stage 2: one block sums partials + bias ----------------------
__global__ __launch_bounds__(256) void readout2_kernel(const float* __restrict__ partial,
                                                       const float* __restrict__ b,
                                                       float* __restrict__ out) {
    __shared__ float wsum[4];
    const int lane = threadIdx.x & 63;
    const int wid  = threadIdx.x >> 6;
    float v = 0.f;
    for (int i = threadIdx.x; i < R1_BLOCKS; i += 256) v += partial[i];
#pragma unroll
    for (int o = 32; o > 0; o >>= 1) v += __shfl_xor(v, o, 64);
    if (lane == 0) wsum[wid] = v;
    __syncthreads();
    if (threadIdx.x == 0)
        out[0] = (wsum[0] + wsum[1]) + (wsum[2] + wsum[3]) + b[0];
}

extern "C" void kernel_launch(void* const* d_in, const int* in_sizes, int n_in,
                              void* d_out, int out_size, void* d_ws, size_t ws_size,
                              hipStream_t stream) {
    const float* nodes     = (const float*)d_in[0];
    const int*   senders   = (const int*)d_in[1];
    const int*   receivers = (const int*)d_in[2];
    const int*   etypes    = (const int*)d_in[3];
    // d_in[4] = n_node (single graph; unused)
    const float* kernels   = (const float*)d_in[5];
    const float* dense_w   = (const float*)d_in[6];
    const float* dense_b   = (const float*)d_in[7];
    float* out = (float*)d_out;

    float* agg     = (float*)d_ws;                  // NN x HID
    float* sdeg    = agg + (size_t)NN * HID;        // NN
    float* rdeg    = sdeg + NN;                     // NN
    float* partial = rdeg + NN;                     // R1_BLOCKS

    size_t zero_bytes = ((size_t)NN * HID + 2 * (size_t)NN) * sizeof(float);
    (void)hipMemsetAsync(d_ws, 0, zero_bytes, stream);

    deg_kernel<<<(NE + 255) / 256, 256, 0, stream>>>(senders, receivers, sdeg, rdeg);

    const int nchunks = (NE + CHUNK - 1) / CHUNK;          // 1563
    const int cgroups = (nchunks + 3) / 4;                 // 391
    const int blocks  = cgroups * NREL;                    // 3128
    edge_kernel<<<blocks, 256, 0, stream>>>(nodes, senders, receivers, etypes,
                                            kernels, sdeg, agg);

    readout1_kernel<<<R1_BLOCKS, 256, 0, stream>>>(nodes, agg, rdeg, dense_w, partial);
    readout2_kernel<<<1, 256, 0, stream>>>(partial, dense_b, out);
}